// Round 8
// baseline (352.161 us; speedup 1.0000x reference)
//
#include <hip/hip_runtime.h>
#include <hip/hip_bf16.h>

// SubjectLayers: out[b,t,o] = sum_i x[b,t,i] * w[sid[b],i,o] + bias[sid[b],o]
// B=256 T=512 IN=256 OUT=256 S=128, all fp32 in/out.
// R8: VMEM-traffic-minimal config. Diagnosis: chip-wide VECTOR-MEMORY traffic
// (independent of cache level) is the binding resource (~6.3 TB/s); R3/R5
// carried 536 MB (A f32 x2, B x2). This block reads everything ONCE:
// block = 256 rows x 256 cols (full OUT), A 134 + B 67 + stores 134 = 335 MB.
// Mechanics identical to verified R6 (reg-staged A f32->bf16 -> ds_write,
// chunk-major B via global_load_lds, depth-2 counted-vmcnt pipeline), scaled
// to 512 threads / 8 waves, 64 KB LDS -> 2 blocks/CU (16 waves/CU).

#define B_DIM 256
#define T_DIM 512
#define IN_DIM 256
#define OUT_DIM 256
#define S_DIM 128
#define BK 32

typedef __attribute__((ext_vector_type(4))) float f32x4;
typedef __attribute__((ext_vector_type(8))) short s16x8;
typedef __attribute__((ext_vector_type(4))) unsigned short u16x4;

typedef const __attribute__((address_space(1))) unsigned int* gptr_t;
typedef __attribute__((address_space(3))) unsigned int* lptr_t;

static __device__ __forceinline__ unsigned short f2bf(float f) {
  __hip_bfloat16 h = __float2bfloat16(f);
  return __builtin_bit_cast(unsigned short, h);
}

// Pre-pass: wT[s][o][i] = bf16(w[s][i][o]). 64x64 tiles via LDS.
__global__ __launch_bounds__(256) void wt_transpose(const float* __restrict__ w,
                                                    unsigned short* __restrict__ wT) {
  __shared__ float tile[64][65];
  int bid = blockIdx.x;
  int s = bid >> 4, ti = (bid >> 2) & 3, to = bid & 3;
  const float* wp = w + (size_t)s * IN_DIM * OUT_DIM;
  unsigned short* op = wT + (size_t)s * IN_DIM * OUT_DIM;
  int t = threadIdx.x;
  int rr = t >> 6, cc = t & 63;
#pragma unroll
  for (int p = 0; p < 16; ++p) {
    tile[p * 4 + rr][cc] = wp[(size_t)(ti * 64 + p * 4 + rr) * OUT_DIM + to * 64 + cc];
  }
  __syncthreads();
  int orr = t >> 4, i4 = (t & 15) * 4;
#pragma unroll
  for (int p = 0; p < 4; ++p) {
    int ol = p * 16 + orr;  // o within tile
    u16x4 v;
    v[0] = f2bf(tile[i4 + 0][ol]);
    v[1] = f2bf(tile[i4 + 1][ol]);
    v[2] = f2bf(tile[i4 + 2][ol]);
    v[3] = f2bf(tile[i4 + 3][ol]);
    *(u16x4*)(op + (size_t)(to * 64 + ol) * IN_DIM + ti * 64 + i4) = v;
  }
}

// Block = 256 T-rows x 256 O-cols, 512 threads = 8 waves (4m x 2n),
// wave tile 64x128 (4fm x 8fn frags of 16x16x32 bf16 MFMA). 8 K-steps, BK=32.
// A LDS (bf16): row r = 64 B; 16B chunk c stored at c ^ ((r>>1)&3).
// B LDS (bf16): chunk-major [kq][col][16B], byte = kq*4096 + col*16.
__global__ __launch_bounds__(512, 4) void subj_gemm_v8(
    const float* __restrict__ x, const int* __restrict__ sid,
    const unsigned short* __restrict__ wT, const float* __restrict__ bias,
    float* __restrict__ out) {
  __shared__ __align__(16) unsigned short lA[2][256 * BK];     // 16 KB x2
  __shared__ __align__(16) unsigned short lB[2][4 * OUT_DIM * 8];  // 16 KB x2

  // bijective XCD chunking (512 % 8 == 0): 64 consecutive bids per XCD;
  // the two blocks of one batch stay adjacent -> shared wT[s] in one L2.
  unsigned wg = blockIdx.x;
  unsigned bid = (wg & 7u) * 64u + (wg >> 3);
  int batch = bid >> 1;
  int mt = bid & 1;
  int s = sid[batch];

  int t = threadIdx.x;
  int l = t & 63, wv = t >> 6;
  int wm = (wv >> 1) * 64, wn = (wv & 1) * 128;

  const float* xbase = x + ((size_t)batch * T_DIM + mt * 256) * IN_DIM;
  const unsigned short* wbase = wT + (size_t)s * IN_DIM * OUT_DIM;

  // ---- A reg staging: thread t, i=0..3: row = i*64 + (t>>3), f32 cols (t&7)*4..+3
  const float* ag = xbase + (size_t)(t >> 3) * IN_DIM + (t & 7) * 4;
  // A ds_write byte offset: row*64 + swz_chunk*16 + half*8  (+i*4096 per i)
  const unsigned awr = (unsigned)(t >> 3) * 64 +
                       ((((t & 7) >> 1) ^ ((t >> 4) & 3)) << 4) + (t & 1) * 8;

  f32x4 areg[4], areg2[4];

#define ISSUE_A(dst, stp)                                                     \
  do {                                                                        \
    _Pragma("unroll") for (int i = 0; i < 4; ++i)                             \
        dst[i] = *(const f32x4*)(ag + (size_t)i * 64 * IN_DIM + (stp) * BK);  \
  } while (0)
#define CVT_WRITE(src, bufi)                                                  \
  do {                                                                        \
    _Pragma("unroll") for (int i = 0; i < 4; ++i) {                           \
      u16x4 h;                                                                \
      h[0] = f2bf(src[i][0]); h[1] = f2bf(src[i][1]);                         \
      h[2] = f2bf(src[i][2]); h[3] = f2bf(src[i][3]);                         \
      *(u16x4*)((unsigned char*)&lA[bufi][0] + awr + i * 4096) = h;           \
    }                                                                         \
  } while (0)
  // ---- B staging: wave wv stages kq=(wv&3), cols (wv>>2)*128 + j*64 + l
#define ISSUE_B(bufi, stp)                                                    \
  do {                                                                        \
    _Pragma("unroll") for (int j = 0; j < 2; ++j)                             \
        __builtin_amdgcn_global_load_lds(                                     \
            (gptr_t)(wbase +                                                  \
                     (size_t)((wv >> 2) * 128 + j * 64 + l) * IN_DIM +        \
                     (stp) * BK + (wv & 3) * 8),                              \
            (lptr_t)(&lB[bufi][(wv & 3) * 2048 +                              \
                               ((wv >> 2) * 128 + j * 64) * 8]),              \
            16, 0, 0);                                                        \
  } while (0)

  int fr = l & 15, kq = l >> 4;
  int r0 = kq * 4;  // C/D row group

  unsigned aBase = (unsigned)(size_t)(lptr_t)&lA[0][0];
  unsigned bBase = (unsigned)(size_t)(lptr_t)&lB[0][0];
  unsigned aoff[4], boff[8];
#pragma unroll
  for (int fm = 0; fm < 4; ++fm) {
    int row = wm + fm * 16 + fr;
    aoff[fm] = row * 64 + ((kq ^ ((fr >> 1) & 3)) << 4);
  }
#pragma unroll
  for (int fn = 0; fn < 8; ++fn)
    boff[fn] = kq * 4096 + (wn + fn * 16 + fr) * 16;

  f32x4 acc[4][8];
#pragma unroll
  for (int i = 0; i < 4; ++i)
#pragma unroll
    for (int j = 0; j < 8; ++j) acc[i][j] = (f32x4){0.f, 0.f, 0.f, 0.f};

  // ---- prologue (loop-entry queue invariant: [B0:2, A2:4, B1:2])
  ISSUE_A(areg, 0);
  ISSUE_A(areg2, 1);
  asm volatile("s_waitcnt vmcnt(4)" ::: "memory");  // A0 regs ready
  CVT_WRITE(areg, 0);
  ISSUE_B(0, 0);
  asm volatile("s_waitcnt vmcnt(2)" ::: "memory");  // A1 regs ready
  CVT_WRITE(areg2, 1);
  ISSUE_A(areg, 2);
  ISSUE_B(1, 1);
  asm volatile("s_waitcnt lgkmcnt(0)" ::: "memory");  // A0/A1 LDS writes done
  __builtin_amdgcn_sched_barrier(0);

#pragma unroll
  for (int stp = 0; stp < 8; ++stp) {
    const int bf = stp & 1;
    const unsigned ab = aBase + bf * 16384;
    const unsigned bb = bBase + bf * 16384;
    // steady queue: [B(s):2, A(s+2):4, B(s+1):2] -> drain B(s) only
    if (stp < 6)       asm volatile("s_waitcnt vmcnt(6)" ::: "memory");
    else if (stp == 6) asm volatile("s_waitcnt vmcnt(2)" ::: "memory");
    else               asm volatile("s_waitcnt vmcnt(0)" ::: "memory");
    asm volatile("s_barrier" ::: "memory");  // buf[bf] fully staged

    s16x8 af[4], bfr[8];
#pragma unroll
    for (int fm = 0; fm < 4; ++fm)
      asm volatile("ds_read_b128 %0, %1" : "=v"(af[fm]) : "v"(ab + aoff[fm]));
#pragma unroll
    for (int fn = 0; fn < 8; ++fn)
      asm volatile("ds_read_b128 %0, %1" : "=v"(bfr[fn]) : "v"(bb + boff[fn]));
    asm volatile("s_waitcnt lgkmcnt(0)" ::: "memory");
    __builtin_amdgcn_sched_barrier(0);
    asm volatile("s_barrier" ::: "memory");  // all waves done reading buf[bf]

    if (stp < 6) {
      asm volatile("s_waitcnt vmcnt(2)" ::: "memory");  // A(s+2) regs ready
      CVT_WRITE(areg, bf);                              // A(s+2) -> buf[bf]
      if (stp < 5) ISSUE_A(areg, stp + 3);
      ISSUE_B(bf, stp + 2);
      __builtin_amdgcn_sched_barrier(0);
    }

#pragma unroll
    for (int fm = 0; fm < 4; ++fm)
#pragma unroll
      for (int fn = 0; fn < 8; ++fn)
        acc[fm][fn] = __builtin_amdgcn_mfma_f32_16x16x32_bf16(
            af[fm], bfr[fn], acc[fm][fn], 0, 0, 0);
  }

  // ---- epilogue: bias + store (fm -> r -> fn; 16-lane 64B bursts)
  const float* bp = bias + (size_t)s * OUT_DIM + wn;
  float bv[8];
#pragma unroll
  for (int fn = 0; fn < 8; ++fn) bv[fn] = bp[fn * 16 + fr];

  float* orow = out + ((size_t)batch * T_DIM + mt * 256 + wm) * OUT_DIM + wn;
#pragma unroll
  for (int fm = 0; fm < 4; ++fm)
#pragma unroll
    for (int r = 0; r < 4; ++r)
#pragma unroll
      for (int fn = 0; fn < 8; ++fn)
        orow[(size_t)(fm * 16 + r0 + r) * OUT_DIM + fn * 16 + fr] =
            acc[fm][fn][r] + bv[fn];
#undef ISSUE_A
#undef ISSUE_B
#undef CVT_WRITE
}

// Emergency fallback if d_ws is too small: correct but slow.
__global__ __launch_bounds__(256) void naive_kernel(
    const float* __restrict__ x, const int* __restrict__ sid,
    const float* __restrict__ w, const float* __restrict__ bias,
    float* __restrict__ out) {
  __shared__ float lx[IN_DIM];
  size_t bt = blockIdx.x;
  int batch = (int)(bt / T_DIM);
  int s = sid[batch];
  int o = threadIdx.x;
  lx[o] = x[bt * IN_DIM + o];
  __syncthreads();
  const float* wp = w + (size_t)s * IN_DIM * OUT_DIM + o;
  float acc = bias[(size_t)s * OUT_DIM + o];
  for (int i = 0; i < IN_DIM; ++i) acc += lx[i] * wp[(size_t)i * OUT_DIM];
  out[bt * OUT_DIM + o] = acc;
}

extern "C" void kernel_launch(void* const* d_in, const int* in_sizes, int n_in,
                              void* d_out, int out_size, void* d_ws, size_t ws_size,
                              hipStream_t stream) {
  const float* x = (const float*)d_in[0];
  const int* sid = (const int*)d_in[1];
  const float* w = (const float*)d_in[2];
  const float* bias = (const float*)d_in[3];
  float* out = (float*)d_out;

  size_t need = (size_t)S_DIM * IN_DIM * OUT_DIM * sizeof(unsigned short);
  if (ws_size >= need) {
    unsigned short* wT = (unsigned short*)d_ws;
    wt_transpose<<<dim3(S_DIM * 16), dim3(256), 0, stream>>>(w, wT);
    subj_gemm_v8<<<dim3(512), dim3(512), 0, stream>>>(x, sid, wT, bias, out);
  } else {
    naive_kernel<<<dim3(B_DIM * T_DIM), dim3(256), 0, stream>>>(x, sid, w, bias, out);
  }
}

// Round 9
// 97.505 us; speedup vs baseline: 3.6117x; 3.6117x over previous
//
#include <hip/hip_runtime.h>
#include <hip/hip_bf16.h>

// SubjectLayers: out[b,t,o] = sum_i x[b,t,i] * w[sid[b],i,o] + bias[sid[b],o]
// B=256 T=512 IN=256 OUT=256 S=128, all fp32 in/out.
// R9 = R3 (82us best) with the sync discipline fixed:
//  - __builtin_amdgcn_s_barrier() instead of asm("s_barrier":::"memory")
//  - clobber-FREE s_waitcnt asm + sched_barrier(0) pins (m201 template style;
//    "memory" clobbers invited compiler-inserted vmcnt(0) drains = 50% duty)
//  - B LDS chunk-major (R6-verified conflict-free)
//  - s_setprio(1) around MFMA cluster (T5)

#define B_DIM 256
#define T_DIM 512
#define IN_DIM 256
#define OUT_DIM 256
#define S_DIM 128
#define BK 32

typedef __attribute__((ext_vector_type(4))) float f32x4;
typedef __attribute__((ext_vector_type(8))) short s16x8;
typedef __attribute__((ext_vector_type(4))) unsigned short u16x4;

typedef const __attribute__((address_space(1))) unsigned int* gptr_t;
typedef __attribute__((address_space(3))) unsigned int* lptr_t;

static __device__ __forceinline__ unsigned short f2bf(float f) {
  __hip_bfloat16 h = __float2bfloat16(f);
  return __builtin_bit_cast(unsigned short, h);
}

// Pre-pass: wT[s][o][i] = bf16(w[s][i][o]). 64x64 tiles via LDS.
__global__ __launch_bounds__(256) void wt_transpose(const float* __restrict__ w,
                                                    unsigned short* __restrict__ wT) {
  __shared__ float tile[64][65];
  int bid = blockIdx.x;
  int s = bid >> 4, ti = (bid >> 2) & 3, to = bid & 3;
  const float* wp = w + (size_t)s * IN_DIM * OUT_DIM;
  unsigned short* op = wT + (size_t)s * IN_DIM * OUT_DIM;
  int t = threadIdx.x;
  int rr = t >> 6, cc = t & 63;
#pragma unroll
  for (int p = 0; p < 16; ++p) {
    tile[p * 4 + rr][cc] = wp[(size_t)(ti * 64 + p * 4 + rr) * OUT_DIM + to * 64 + cc];
  }
  __syncthreads();
  int orr = t >> 4, i4 = (t & 15) * 4;
#pragma unroll
  for (int p = 0; p < 4; ++p) {
    int ol = p * 16 + orr;  // o within tile
    u16x4 v;
    v[0] = f2bf(tile[i4 + 0][ol]);
    v[1] = f2bf(tile[i4 + 1][ol]);
    v[2] = f2bf(tile[i4 + 2][ol]);
    v[3] = f2bf(tile[i4 + 3][ol]);
    *(u16x4*)(op + (size_t)(to * 64 + ol) * IN_DIM + ti * 64 + i4) = v;
  }
}

// Pipelined GEMM. Block = 128 T-rows x 128 O-cols, 4 waves (2m x 2n),
// wave tile 64x64 (4x4 frags of 16x16x32 bf16 MFMA). 8 K-steps of BK=32.
// A LDS: row-major 128B rows, 16B chunk c of row r holds global chunk c^(r&7).
// B LDS: chunk-major [kq 0..3][col 0..127][16B] (conflict-free reads).
__global__ __launch_bounds__(256, 3) void subj_gemm_v9(
    const float* __restrict__ x, const int* __restrict__ sid,
    const unsigned short* __restrict__ wT, const float* __restrict__ bias,
    float* __restrict__ out) {
  __shared__ __align__(16) float lA[2][128 * BK];              // 16 KB x2
  __shared__ __align__(16) unsigned short lB[2][4 * 128 * 8];  // 8 KB x2

  // pair-swizzle: the two nt-tiles of one (batch,mt) are grid-adjacent
  unsigned wg = blockIdx.x;
  unsigned bid = (wg & ~15u) | ((wg & 7u) << 1) | ((wg >> 3) & 1u);
  int batch = bid >> 3;
  int mt = (bid >> 1) & 3;
  int nt = bid & 1;
  int s = sid[batch];

  int t = threadIdx.x;
  int l = t & 63, wv = t >> 6;
  int wm = (wv >> 1) * 64, wn = (wv & 1) * 64;

  const float* xbase = x + ((size_t)batch * T_DIM + mt * 128) * IN_DIM;
  const unsigned short* wbase =
      wT + (size_t)s * IN_DIM * OUT_DIM + (size_t)(nt * 128) * IN_DIM;

  int a_row = l >> 3;                 // row within instr's 8 rows
  int a_chunk = (l & 7) ^ a_row;      // pre-swizzled source 16B chunk

  // A instr i (0..15, wave does i=wv*4..+3): rows i*8+a_row, dest lA+i*1024B.
  // B instr (wave wv = k-chunk kq, j = col half): cols j*64+l at fixed kq;
  //   dest chunk-major byte = wv*2048 + (j*64)*16 (linear 1KB per instr).
#define STAGEA(buf, stp, i)                                                   \
  __builtin_amdgcn_global_load_lds(                                           \
      (gptr_t)(xbase + (size_t)((i) * 8 + a_row) * IN_DIM + (stp) * BK +      \
               a_chunk * 4),                                                  \
      (lptr_t)(&lA[buf][(i) * 256]), 16, 0, 0)
#define STAGEB(buf, stp, j)                                                   \
  __builtin_amdgcn_global_load_lds(                                           \
      (gptr_t)(wbase + (size_t)((j) * 64 + l) * IN_DIM + (stp) * BK +         \
               wv * 8),                                                       \
      (lptr_t)(&lB[buf][wv * 1024 + (j) * 512]), 16, 0, 0)
#define STAGE(buf, stp)                                                       \
  do {                                                                        \
    STAGEA(buf, stp, wv * 4 + 0); STAGEA(buf, stp, wv * 4 + 1);               \
    STAGEA(buf, stp, wv * 4 + 2); STAGEA(buf, stp, wv * 4 + 3);               \
    STAGEB(buf, stp, 0); STAGEB(buf, stp, 1);                                 \
  } while (0)

  int fr = l & 15, kq = l >> 4;
  int r0 = kq * 4;  // C/D row group

  unsigned aBase = (unsigned)(size_t)(lptr_t)&lA[0][0];
  unsigned bBase = (unsigned)(size_t)(lptr_t)&lB[0][0];
  unsigned aoff[4][2], boff[4];
#pragma unroll
  for (int fm = 0; fm < 4; ++fm) {
    int row = wm + fm * 16 + fr;
    aoff[fm][0] = row * 128 + (((2 * kq) ^ (fr & 7)) << 4);
    aoff[fm][1] = row * 128 + (((2 * kq + 1) ^ (fr & 7)) << 4);
  }
#pragma unroll
  for (int fn = 0; fn < 4; ++fn)
    boff[fn] = kq * 2048 + (wn + fn * 16 + fr) * 16;

  f32x4 acc[4][4];
#pragma unroll
  for (int i = 0; i < 4; ++i)
#pragma unroll
    for (int j = 0; j < 4; ++j) acc[i][j] = (f32x4){0.f, 0.f, 0.f, 0.f};

  STAGE(0, 0);  // 6 loads/wave
  STAGE(1, 1);  // 6 loads/wave

#pragma unroll
  for (int stp = 0; stp < 8; ++stp) {
    const int bf = stp & 1;
    const unsigned ab = aBase + bf * (128 * BK * 4);
    const unsigned bb = bBase + bf * (4 * 128 * 16);
    // tile stp resident; next tile's 6 loads stay in flight (counted, no
    // "memory" clobber -> no compiler-inserted drain)
    if (stp < 7) asm volatile("s_waitcnt vmcnt(6)");
    else         asm volatile("s_waitcnt vmcnt(0)");
    __builtin_amdgcn_sched_barrier(0);
    __builtin_amdgcn_s_barrier();       // all waves' loads for stp staged
    __builtin_amdgcn_sched_barrier(0);

    f32x4 alo[4], ahi[4];
    s16x8 bfrag[4];
#pragma unroll
    for (int fm = 0; fm < 4; ++fm) {
      asm volatile("ds_read_b128 %0, %1" : "=v"(alo[fm]) : "v"(ab + aoff[fm][0]));
      asm volatile("ds_read_b128 %0, %1" : "=v"(ahi[fm]) : "v"(ab + aoff[fm][1]));
    }
#pragma unroll
    for (int fn = 0; fn < 4; ++fn) {
      asm volatile("ds_read_b128 %0, %1" : "=v"(bfrag[fn]) : "v"(bb + boff[fn]));
    }
    asm volatile("s_waitcnt lgkmcnt(0)");
    __builtin_amdgcn_sched_barrier(0);
    __builtin_amdgcn_s_barrier();       // all waves done reading buf[bf]
    __builtin_amdgcn_sched_barrier(0);

    if (stp < 6) STAGE(bf, stp + 2);    // overwrite buf[bf] for step stp+2
    __builtin_amdgcn_sched_barrier(0);

    __builtin_amdgcn_s_setprio(1);
    s16x8 af[4];
#pragma unroll
    for (int fm = 0; fm < 4; ++fm) {
      s16x8 a;
      a[0] = (short)f2bf(alo[fm][0]); a[1] = (short)f2bf(alo[fm][1]);
      a[2] = (short)f2bf(alo[fm][2]); a[3] = (short)f2bf(alo[fm][3]);
      a[4] = (short)f2bf(ahi[fm][0]); a[5] = (short)f2bf(ahi[fm][1]);
      a[6] = (short)f2bf(ahi[fm][2]); a[7] = (short)f2bf(ahi[fm][3]);
      af[fm] = a;
    }
#pragma unroll
    for (int fm = 0; fm < 4; ++fm)
#pragma unroll
      for (int fn = 0; fn < 4; ++fn)
        acc[fm][fn] = __builtin_amdgcn_mfma_f32_16x16x32_bf16(
            af[fm], bfrag[fn], acc[fm][fn], 0, 0, 0);
    __builtin_amdgcn_s_setprio(0);
  }

  // epilogue: add bias, store (16-lane groups write 64B contiguous)
  const float* bp = bias + (size_t)s * OUT_DIM;
  float bv[4];
#pragma unroll
  for (int fn = 0; fn < 4; ++fn) bv[fn] = bp[nt * 128 + wn + fn * 16 + fr];

  float* orow =
      out + ((size_t)batch * T_DIM + mt * 128 + wm) * OUT_DIM + nt * 128 + wn;
#pragma unroll
  for (int fm = 0; fm < 4; ++fm)
#pragma unroll
    for (int fn = 0; fn < 4; ++fn)
#pragma unroll
      for (int r = 0; r < 4; ++r)
        orow[(size_t)(fm * 16 + r0 + r) * OUT_DIM + fn * 16 + fr] =
            acc[fm][fn][r] + bv[fn];
#undef STAGE
#undef STAGEA
#undef STAGEB
}

// Emergency fallback if d_ws is too small: correct but slow.
__global__ __launch_bounds__(256) void naive_kernel(
    const float* __restrict__ x, const int* __restrict__ sid,
    const float* __restrict__ w, const float* __restrict__ bias,
    float* __restrict__ out) {
  __shared__ float lx[IN_DIM];
  size_t bt = blockIdx.x;
  int batch = (int)(bt / T_DIM);
  int s = sid[batch];
  int o = threadIdx.x;
  lx[o] = x[bt * IN_DIM + o];
  __syncthreads();
  const float* wp = w + (size_t)s * IN_DIM * OUT_DIM + o;
  float acc = bias[(size_t)s * OUT_DIM + o];
  for (int i = 0; i < IN_DIM; ++i) acc += lx[i] * wp[(size_t)i * OUT_DIM];
  out[bt * OUT_DIM + o] = acc;
}

extern "C" void kernel_launch(void* const* d_in, const int* in_sizes, int n_in,
                              void* d_out, int out_size, void* d_ws, size_t ws_size,
                              hipStream_t stream) {
  const float* x = (const float*)d_in[0];
  const int* sid = (const int*)d_in[1];
  const float* w = (const float*)d_in[2];
  const float* bias = (const float*)d_in[3];
  float* out = (float*)d_out;

  size_t need = (size_t)S_DIM * IN_DIM * OUT_DIM * sizeof(unsigned short);
  if (ws_size >= need) {
    unsigned short* wT = (unsigned short*)d_ws;
    wt_transpose<<<dim3(S_DIM * 16), dim3(256), 0, stream>>>(w, wT);
    subj_gemm_v9<<<dim3(2048), dim3(256), 0, stream>>>(x, sid, wT, bias, out);
  } else {
    naive_kernel<<<dim3(B_DIM * T_DIM), dim3(256), 0, stream>>>(x, sid, w, bias, out);
  }
}

// Round 10
// 81.915 us; speedup vs baseline: 4.2991x; 1.1903x over previous
//
#include <hip/hip_runtime.h>
#include <hip/hip_bf16.h>

// SubjectLayers: out[b,t,o] = sum_i x[b,t,i] * w[sid[b],i,o] + bias[sid[b],o]
// B=256 T=512 IN=256 OUT=256 S=128, all fp32 in/out.
// R10: SEQUENTIAL-HBM design. Theory: per-CU memory concurrency is capped
// (~4KB in flight); scattered 128B-row reads pay full ~900cy latency ->
// ~3 TB/s wall seen in R2-R9. Fix: each block reads a CONTIGUOUS 64KB x
// region (64 rows x full K) once into LDS (bf16), writes a contiguous 64KB
// out region; only B (L2-resident, chunk-major wT2) loops over K.

#define B_DIM 256
#define T_DIM 512
#define IN_DIM 256
#define OUT_DIM 256
#define S_DIM 128

typedef __attribute__((ext_vector_type(4))) float f32x4;
typedef __attribute__((ext_vector_type(8))) short s16x8;
typedef __attribute__((ext_vector_type(8))) unsigned short u16x8;
typedef __attribute__((ext_vector_type(4))) unsigned short u16x4;

typedef const __attribute__((address_space(1))) unsigned int* gptr_t;
typedef __attribute__((address_space(3))) unsigned int* lptr_t;

static __device__ __forceinline__ unsigned short f2bf(float f) {
  __hip_bfloat16 h = __float2bfloat16(f);
  return __builtin_bit_cast(unsigned short, h);
}

// Pre-pass: chunk-major transposed weights.
// wT2 element (s, o, i) lives at ((s*32 + (i>>3))*256 + o)*8 + (i&7):
// for a fixed k-chunk, the 256 o-columns are 16B each, CONTIGUOUS 4KB runs.
__global__ __launch_bounds__(256) void wt_transpose(const float* __restrict__ w,
                                                    unsigned short* __restrict__ wT2) {
  __shared__ float tile[64][65];
  int bid = blockIdx.x;
  int s = bid >> 4, ti = (bid >> 2) & 3, to = bid & 3;
  const float* wp = w + (size_t)s * IN_DIM * OUT_DIM;
  int t = threadIdx.x;
  int rr = t >> 6, cc = t & 63;
#pragma unroll
  for (int p = 0; p < 16; ++p) {
    tile[p * 4 + rr][cc] = wp[(size_t)(ti * 64 + p * 4 + rr) * OUT_DIM + to * 64 + cc];
  }
  __syncthreads();
  int orr = t >> 4, i4 = (t & 15) * 4;
#pragma unroll
  for (int p = 0; p < 4; ++p) {
    int ol = p * 16 + orr;        // o within 64-tile
    int i0 = ti * 64 + i4;        // global i of first of 4
    u16x4 v;
    v[0] = f2bf(tile[i4 + 0][ol]);
    v[1] = f2bf(tile[i4 + 1][ol]);
    v[2] = f2bf(tile[i4 + 2][ol]);
    v[3] = f2bf(tile[i4 + 3][ol]);
    size_t idx = ((size_t)(s * 32 + (i0 >> 3)) * OUT_DIM + (to * 64 + ol)) * 8 + (i0 & 7);
    *(u16x4*)(wT2 + idx) = v;
  }
}

// Block = 64 T-rows x 256 O-cols, 512 threads = 8 waves (2m x 4n),
// wave tile 32x64 (2fm x 4fn frags of 16x16x32 bf16 MFMA). 8 K-steps of 32.
// A LDS (bf16, 32KB, single buffer): row r = 512B; 16B chunk c stored at
//   byte r*512 + ((c ^ (r&15))<<4)  (c = k/8, 32 chunks).
// B LDS (bf16, 16KB x2): chunk-major byte = kq*4096 + col*16.
__global__ __launch_bounds__(512, 4) void subj_gemm_v10(
    const float* __restrict__ x, const int* __restrict__ sid,
    const unsigned short* __restrict__ wT2, const float* __restrict__ bias,
    float* __restrict__ out) {
  __shared__ __align__(16) unsigned short lA[64 * IN_DIM];       // 32 KB
  __shared__ __align__(16) unsigned short lB[2][4 * OUT_DIM * 8];  // 16 KB x2

  // bijective XCD chunking (2048 % 8 == 0): 256 consecutive bids per XCD ->
  // whole batches (8 row-blocks) per XCD, contiguous x regions, wT2 L2-local.
  unsigned wg = blockIdx.x;
  unsigned bid = (wg & 7u) * 256u + (wg >> 3);
  int batch = bid >> 3;
  int rb = bid & 7;  // 64-row segment
  int s = sid[batch];

  int t = threadIdx.x;
  int l = t & 63, wv = t >> 6;
  int wm = (wv >> 2) * 32, wn = (wv & 3) * 64;

  const float* xbase = x + ((size_t)batch * T_DIM + rb * 64) * IN_DIM;  // 64KB region
  const unsigned short* wbase = wT2 + (size_t)s * 32 * OUT_DIM * 8;

  // ---- A load: thread t, j=0..3: two f32x4 at bytes j*16384 + t*32 (+16).
  // Thread (t,j) owns bf16 chunk cf = j*512 + t: row = cf>>5, c = cf&31.
  f32x4 a0[4], a1[4];
#define ISSUE_A()                                                             \
  do {                                                                        \
    _Pragma("unroll") for (int j = 0; j < 4; ++j) {                           \
      const float* p = xbase + (size_t)j * 4096 + t * 8;                      \
      a0[j] = *(const f32x4*)p;                                               \
      a1[j] = *(const f32x4*)(p + 4);                                         \
    }                                                                         \
  } while (0)
#define CVT_WRITE_A()                                                         \
  do {                                                                        \
    _Pragma("unroll") for (int j = 0; j < 4; ++j) {                           \
      int cf = j * 512 + t;                                                   \
      int row = cf >> 5, c = cf & 31;                                         \
      u16x8 h;                                                                \
      h[0] = f2bf(a0[j][0]); h[1] = f2bf(a0[j][1]);                           \
      h[2] = f2bf(a0[j][2]); h[3] = f2bf(a0[j][3]);                           \
      h[4] = f2bf(a1[j][0]); h[5] = f2bf(a1[j][1]);                           \
      h[6] = f2bf(a1[j][2]); h[7] = f2bf(a1[j][3]);                           \
      *(u16x8*)((unsigned char*)&lA[0] + row * 512 +                          \
                ((c ^ (row & 15)) << 4)) = h;                                 \
    }                                                                         \
  } while (0)
  // ---- B stage: wave wv: k-chunk kq=(wv&3), cols (wv>>2)*128 + j*64 + l.
  // Source is CONTIGUOUS 1KB per instr (chunk-major wT2). Dest linear.
#define ISSUE_B(bufi, stp)                                                    \
  do {                                                                        \
    _Pragma("unroll") for (int j = 0; j < 2; ++j) {                           \
      int col = (wv >> 2) * 128 + j * 64;                                     \
      __builtin_amdgcn_global_load_lds(                                       \
          (gptr_t)(wbase + ((size_t)((stp) * 4 + (wv & 3)) * OUT_DIM +        \
                            col + l) * 8),                                    \
          (lptr_t)(&lB[bufi][((wv & 3) * OUT_DIM + col) * 8]), 16, 0, 0);     \
    }                                                                         \
  } while (0)

  int fr = l & 15, kq = l >> 4;
  int r0 = kq * 4;  // C/D row group

  unsigned aBase = (unsigned)(size_t)(lptr_t)&lA[0];
  unsigned bBase = (unsigned)(size_t)(lptr_t)&lB[0][0];
  unsigned arow[2];
#pragma unroll
  for (int fm = 0; fm < 2; ++fm) arow[fm] = (wm + fm * 16 + fr) * 512;
  unsigned boff[4];
#pragma unroll
  for (int fn = 0; fn < 4; ++fn)
    boff[fn] = kq * 4096 + (wn + fn * 16 + fr) * 16;

  f32x4 acc[2][4];
#pragma unroll
  for (int i = 0; i < 2; ++i)
#pragma unroll
    for (int j = 0; j < 4; ++j) acc[i][j] = (f32x4){0.f, 0.f, 0.f, 0.f};

  // ---- prologue: A stream (8 loads) + first two B tiles
  ISSUE_A();
  ISSUE_B(0, 0);
  ISSUE_B(1, 1);
  asm volatile("s_waitcnt vmcnt(4)");  // A regs ready (B0,B1 in flight)
  __builtin_amdgcn_sched_barrier(0);
  CVT_WRITE_A();
  asm volatile("s_waitcnt lgkmcnt(0)");
  __builtin_amdgcn_sched_barrier(0);
  __builtin_amdgcn_s_barrier();  // A fully staged

#pragma unroll
  for (int stp = 0; stp < 8; ++stp) {
    const int bf = stp & 1;
    const unsigned bb = bBase + bf * 16384;
    // top-of-step queue: [B(s):2, B(s+1):2] -> drain B(s) only
    if (stp < 7) asm volatile("s_waitcnt vmcnt(2)");
    else         asm volatile("s_waitcnt vmcnt(0)");
    __builtin_amdgcn_sched_barrier(0);
    __builtin_amdgcn_s_barrier();  // B(s) staged by all waves
    __builtin_amdgcn_sched_barrier(0);

    s16x8 af[2], bfr[4];
#pragma unroll
    for (int fm = 0; fm < 2; ++fm) {
      unsigned c = (unsigned)(stp * 4) + kq;
      unsigned ao = arow[fm] + ((c ^ (unsigned)fr) << 4);
      asm volatile("ds_read_b128 %0, %1" : "=v"(af[fm]) : "v"(aBase + ao));
    }
#pragma unroll
    for (int fn = 0; fn < 4; ++fn)
      asm volatile("ds_read_b128 %0, %1" : "=v"(bfr[fn]) : "v"(bb + boff[fn]));
    asm volatile("s_waitcnt lgkmcnt(0)");
    __builtin_amdgcn_sched_barrier(0);
    __builtin_amdgcn_s_barrier();  // all waves done reading lB[bf]
    __builtin_amdgcn_sched_barrier(0);

    if (stp < 6) ISSUE_B(bf, stp + 2);  // refill lB[bf] for step stp+2
    __builtin_amdgcn_sched_barrier(0);

    __builtin_amdgcn_s_setprio(1);
#pragma unroll
    for (int fm = 0; fm < 2; ++fm)
#pragma unroll
      for (int fn = 0; fn < 4; ++fn)
        acc[fm][fn] = __builtin_amdgcn_mfma_f32_16x16x32_bf16(
            af[fm], bfr[fn], acc[fm][fn], 0, 0, 0);
    __builtin_amdgcn_s_setprio(0);
  }

  // ---- epilogue: bias + store (contiguous 64KB block region)
  const float* bp = bias + (size_t)s * OUT_DIM;
  float bv[4];
#pragma unroll
  for (int fn = 0; fn < 4; ++fn) bv[fn] = bp[wn + fn * 16 + fr];

  float* orow = out + ((size_t)batch * T_DIM + rb * 64 + wm) * OUT_DIM + wn;
#pragma unroll
  for (int fm = 0; fm < 2; ++fm)
#pragma unroll
    for (int r = 0; r < 4; ++r)
#pragma unroll
      for (int fn = 0; fn < 4; ++fn)
        orow[(size_t)(fm * 16 + r0 + r) * OUT_DIM + fn * 16 + fr] =
            acc[fm][fn][r] + bv[fn];
#undef ISSUE_A
#undef CVT_WRITE_A
#undef ISSUE_B
}

// Emergency fallback if d_ws is too small: correct but slow.
__global__ __launch_bounds__(256) void naive_kernel(
    const float* __restrict__ x, const int* __restrict__ sid,
    const float* __restrict__ w, const float* __restrict__ bias,
    float* __restrict__ out) {
  __shared__ float lx[IN_DIM];
  size_t bt = blockIdx.x;
  int batch = (int)(bt / T_DIM);
  int s = sid[batch];
  int o = threadIdx.x;
  lx[o] = x[bt * IN_DIM + o];
  __syncthreads();
  const float* wp = w + (size_t)s * IN_DIM * OUT_DIM + o;
  float acc = bias[(size_t)s * OUT_DIM + o];
  for (int i = 0; i < IN_DIM; ++i) acc += lx[i] * wp[(size_t)i * OUT_DIM];
  out[bt * OUT_DIM + o] = acc;
}

extern "C" void kernel_launch(void* const* d_in, const int* in_sizes, int n_in,
                              void* d_out, int out_size, void* d_ws, size_t ws_size,
                              hipStream_t stream) {
  const float* x = (const float*)d_in[0];
  const int* sid = (const int*)d_in[1];
  const float* w = (const float*)d_in[2];
  const float* bias = (const float*)d_in[3];
  float* out = (float*)d_out;

  size_t need = (size_t)S_DIM * IN_DIM * OUT_DIM * sizeof(unsigned short);
  if (ws_size >= need) {
    unsigned short* wT2 = (unsigned short*)d_ws;
    wt_transpose<<<dim3(S_DIM * 16), dim3(256), 0, stream>>>(w, wT2);
    subj_gemm_v10<<<dim3(2048), dim3(512), 0, stream>>>(x, sid, wT2, bias, out);
  } else {
    naive_kernel<<<dim3(B_DIM * T_DIM), dim3(256), 0, stream>>>(x, sid, w, bias, out);
  }
}

// Round 11
// 79.060 us; speedup vs baseline: 4.4544x; 1.0361x over previous
//
#include <hip/hip_runtime.h>
#include <hip/hip_bf16.h>

// SubjectLayers: out[b,t,o] = sum_i x[b,t,i] * w[sid[b],i,o] + bias[sid[b],o]
// B=256 T=512 IN=256 OUT=256 S=128, all fp32 in/out.
// R11: ISSUE-CONTINUITY design. Model from R1-R10: per-CU VMEM throughput is
// ~10-12 B/cyc when issue is bursty/barriered (all rounds), 21 B/cyc when
// continuous (m97). So: A staged once per block (bf16 LDS, 1 barrier total),
// B direct-to-register from chunk-major wT2 (L2-hot, 2-deep ping-pong, NO
// barriers in K-loop), small footprint (32KB LDS) -> 3 blocks/CU overlap
// each other's staging bursts.

#define B_DIM 256
#define T_DIM 512
#define IN_DIM 256
#define OUT_DIM 256
#define S_DIM 128

typedef __attribute__((ext_vector_type(4))) float f32x4;
typedef __attribute__((ext_vector_type(8))) short s16x8;
typedef __attribute__((ext_vector_type(8))) unsigned short u16x8;
typedef __attribute__((ext_vector_type(4))) unsigned short u16x4;

static __device__ __forceinline__ unsigned short f2bf(float f) {
  __hip_bfloat16 h = __float2bfloat16(f);
  return __builtin_bit_cast(unsigned short, h);
}

// Pre-pass: chunk-major transposed weights (identical to R10).
// wT2 element (s, o, i) at ((s*32 + (i>>3))*256 + o)*8 + (i&7).
__global__ __launch_bounds__(256) void wt_transpose(const float* __restrict__ w,
                                                    unsigned short* __restrict__ wT2) {
  __shared__ float tile[64][65];
  int bid = blockIdx.x;
  int s = bid >> 4, ti = (bid >> 2) & 3, to = bid & 3;
  const float* wp = w + (size_t)s * IN_DIM * OUT_DIM;
  int t = threadIdx.x;
  int rr = t >> 6, cc = t & 63;
#pragma unroll
  for (int p = 0; p < 16; ++p) {
    tile[p * 4 + rr][cc] = wp[(size_t)(ti * 64 + p * 4 + rr) * OUT_DIM + to * 64 + cc];
  }
  __syncthreads();
  int orr = t >> 4, i4 = (t & 15) * 4;
#pragma unroll
  for (int p = 0; p < 4; ++p) {
    int ol = p * 16 + orr;        // o within 64-tile
    int i0 = ti * 64 + i4;        // global i of first of 4
    u16x4 v;
    v[0] = f2bf(tile[i4 + 0][ol]);
    v[1] = f2bf(tile[i4 + 1][ol]);
    v[2] = f2bf(tile[i4 + 2][ol]);
    v[3] = f2bf(tile[i4 + 3][ol]);
    size_t idx = ((size_t)(s * 32 + (i0 >> 3)) * OUT_DIM + (to * 64 + ol)) * 8 + (i0 & 7);
    *(u16x4*)(wT2 + idx) = v;
  }
}

// Block = 64 T-rows x 256 O-cols, 256 threads = 4 waves, wave = 64 rows x
// 64 cols (4fm x 4fn frags of 16x16x32 bf16 MFMA). 8 K-steps of 32.
// A LDS (bf16, 32KB, staged once): row r = 512B; chunk c (16B) at byte
//   r*512 + ((c ^ (r&15))<<4)   [R10-verified: 0 bank conflicts]
// B: DIRECT global->reg, 2-deep named ping-pong, no barriers.
__global__ __launch_bounds__(256) void subj_gemm_v11(
    const float* __restrict__ x, const int* __restrict__ sid,
    const unsigned short* __restrict__ wT2, const float* __restrict__ bias,
    float* __restrict__ out) {
  __shared__ __align__(16) unsigned short lA[64 * IN_DIM];  // 32 KB

  // bijective XCD chunking: 256 consecutive bids per XCD (32 whole batches)
  unsigned wg = blockIdx.x;
  unsigned bid = (wg & 7u) * 256u + (wg >> 3);
  int batch = bid >> 3;
  int rb = bid & 7;  // 64-row segment
  int s = sid[batch];

  int t = threadIdx.x;
  int l = t & 63, wv = t >> 6;
  int wn = wv * 64;               // wave's 64-col slice; all waves share rows
  int fr = l & 15, kq = l >> 4;
  int r0 = kq * 4;                // C/D row group

  const float* xbase = x + ((size_t)batch * T_DIM + rb * 64) * IN_DIM;  // 64KB
  const unsigned short* wbase = wT2 + (size_t)s * 32 * OUT_DIM * 8;

  // ---- B fragment loader: k-chunk stp*4+kq, cols wn+fn*16+fr; 16B contiguous
#define LOADB(dst, stp)                                                       \
  do {                                                                        \
    _Pragma("unroll") for (int fn = 0; fn < 4; ++fn)                          \
        dst[fn] = *(const s16x8*)(wbase +                                     \
                                  ((size_t)((stp) * 4 + kq) * OUT_DIM + wn +  \
                                   fn * 16 + fr) * 8);                        \
  } while (0)

  // ---- issue first B tile immediately (L2 latency hides under A staging)
  s16x8 bA[4], bB[4];
  LOADB(bA, 0);

  // ---- A staging: 16 f32x4 loads covering 64KB, cvt to bf16, swizzled LDS.
  // (j,p): f32 offset j*4096 + t*16 + p*4; chunk pair cf=j*512+2t (p=0,1),
  // cf+1 (p=2,3); row=cf>>5, c=cf&31.
  {
    f32x4 aR[4][4];
#pragma unroll
    for (int j = 0; j < 4; ++j)
#pragma unroll
      for (int p = 0; p < 4; ++p)
        aR[j][p] = *(const f32x4*)(xbase + (size_t)j * 4096 + t * 16 + p * 4);
#pragma unroll
    for (int j = 0; j < 4; ++j)
#pragma unroll
      for (int h = 0; h < 2; ++h) {
        int cf = j * 512 + 2 * t + h;
        int row = cf >> 5, c = cf & 31;
        u16x8 v;
        v[0] = f2bf(aR[j][2 * h][0]); v[1] = f2bf(aR[j][2 * h][1]);
        v[2] = f2bf(aR[j][2 * h][2]); v[3] = f2bf(aR[j][2 * h][3]);
        v[4] = f2bf(aR[j][2 * h + 1][0]); v[5] = f2bf(aR[j][2 * h + 1][1]);
        v[6] = f2bf(aR[j][2 * h + 1][2]); v[7] = f2bf(aR[j][2 * h + 1][3]);
        *(u16x8*)((unsigned char*)&lA[0] + row * 512 + ((c ^ (row & 15)) << 4)) = v;
      }
  }
  __syncthreads();  // the ONLY barrier: A staged for all waves

  f32x4 acc[4][4];
#pragma unroll
  for (int i = 0; i < 4; ++i)
#pragma unroll
    for (int j = 0; j < 4; ++j) acc[i][j] = (f32x4){0.f, 0.f, 0.f, 0.f};

  // ---- barrier-free K-loop: 8 steps, B 2-deep ping-pong, A from LDS.
#define AFRAG(dst, stp)                                                       \
  do {                                                                        \
    _Pragma("unroll") for (int fm = 0; fm < 4; ++fm) {                        \
      int row = fm * 16 + fr;                                                 \
      unsigned c = (unsigned)((stp) * 4 + kq);                                \
      dst[fm] = *(const s16x8*)((const unsigned char*)&lA[0] + row * 512 +    \
                                ((c ^ (unsigned)(row & 15)) << 4));           \
    }                                                                         \
  } while (0)
#define MFMA_STEP(breg)                                                       \
  do {                                                                        \
    _Pragma("unroll") for (int fm = 0; fm < 4; ++fm)                          \
      _Pragma("unroll") for (int fn = 0; fn < 4; ++fn)                        \
          acc[fm][fn] = __builtin_amdgcn_mfma_f32_16x16x32_bf16(              \
              af[fm], breg[fn], acc[fm][fn], 0, 0, 0);                        \
  } while (0)

  s16x8 af[4];
#pragma unroll
  for (int sp = 0; sp < 8; sp += 2) {
    LOADB(bB, sp + 1);          // next B in flight during this step's MFMAs
    AFRAG(af, sp);
    MFMA_STEP(bA);
    if (sp + 2 < 8) LOADB(bA, sp + 2);
    AFRAG(af, sp + 1);
    MFMA_STEP(bB);
  }

  // ---- epilogue: bias + store (16-lane groups, 64B contiguous per fn)
  const float* bp = bias + (size_t)s * OUT_DIM + wn;
  float bv[4];
#pragma unroll
  for (int fn = 0; fn < 4; ++fn) bv[fn] = bp[fn * 16 + fr];

  float* orow = out + ((size_t)batch * T_DIM + rb * 64) * OUT_DIM + wn;
#pragma unroll
  for (int fm = 0; fm < 4; ++fm)
#pragma unroll
    for (int r = 0; r < 4; ++r)
#pragma unroll
      for (int fn = 0; fn < 4; ++fn)
        orow[(size_t)(fm * 16 + r0 + r) * OUT_DIM + fn * 16 + fr] =
            acc[fm][fn][r] + bv[fn];
#undef LOADB
#undef AFRAG
#undef MFMA_STEP
}

// Emergency fallback if d_ws is too small: correct but slow.
__global__ __launch_bounds__(256) void naive_kernel(
    const float* __restrict__ x, const int* __restrict__ sid,
    const float* __restrict__ w, const float* __restrict__ bias,
    float* __restrict__ out) {
  __shared__ float lx[IN_DIM];
  size_t bt = blockIdx.x;
  int batch = (int)(bt / T_DIM);
  int s = sid[batch];
  int o = threadIdx.x;
  lx[o] = x[bt * IN_DIM + o];
  __syncthreads();
  const float* wp = w + (size_t)s * IN_DIM * OUT_DIM + o;
  float acc = bias[(size_t)s * OUT_DIM + o];
  for (int i = 0; i < IN_DIM; ++i) acc += lx[i] * wp[(size_t)i * OUT_DIM];
  out[bt * OUT_DIM + o] = acc;
}

extern "C" void kernel_launch(void* const* d_in, const int* in_sizes, int n_in,
                              void* d_out, int out_size, void* d_ws, size_t ws_size,
                              hipStream_t stream) {
  const float* x = (const float*)d_in[0];
  const int* sid = (const int*)d_in[1];
  const float* w = (const float*)d_in[2];
  const float* bias = (const float*)d_in[3];
  float* out = (float*)d_out;

  size_t need = (size_t)S_DIM * IN_DIM * OUT_DIM * sizeof(unsigned short);
  if (ws_size >= need) {
    unsigned short* wT2 = (unsigned short*)d_ws;
    wt_transpose<<<dim3(S_DIM * 16), dim3(256), 0, stream>>>(w, wT2);
    subj_gemm_v11<<<dim3(2048), dim3(256), 0, stream>>>(x, sid, wT2, bias, out);
  } else {
    naive_kernel<<<dim3(B_DIM * T_DIM), dim3(256), 0, stream>>>(x, sid, w, bias, out);
  }
}